// Round 1
// baseline (615.736 us; speedup 1.0000x reference)
//
#include <hip/hip_runtime.h>

#define N_SAMP 8192
#define D_DIM 6144
#define K_CLS 10
#define CHUNK 32
#define NWIN (N_SAMP / CHUNK)             // 256 windows, always full
#define COLS_PER_BLOCK 1024               // 256 threads * 4 floats
#define NGROUPS (D_DIM / COLS_PER_BLOCK)  // 6  -> grid 1536 = 6 blocks/CU even
#define NBLK (NGROUPS * NWIN)             // 1536 accum blocks
#define PIPE 8                            // outstanding float4 loads per thread

typedef float f4 __attribute__((ext_vector_type(4)));

// Kernel A: 1024-thread atomic-free counting sort by class, with fused
// zero-init of S1/s2sum/ctr (replaces two hipMemsetAsync dispatches).
// sorted[] packs (class<<16 | sample idx), class-contiguous. counts[k] out.
__global__ __launch_bounds__(1024) void build_sort(const int* __restrict__ y,
                                                   int* __restrict__ counts,
                                                   int* __restrict__ sorted,
                                                   float* __restrict__ S1,
                                                   float* __restrict__ s2sum,
                                                   unsigned* __restrict__ ctr) {
    __shared__ int M[K_CLS * 1024];
    __shared__ int wsum[16];
    const int tid = threadIdx.x;
    const int lane = tid & 63;
    const int wid = tid >> 6;

    // ---- fused zero-init: S1 (61440 f) + s2sum (10 f) + arrival ctr ----
    {
        f4 z = {0.f, 0.f, 0.f, 0.f};
        f4* p = (f4*)S1;
#pragma unroll
        for (int i = 0; i < (K_CLS * D_DIM) / (4 * 1024); ++i)  // 15 per thread
            p[i * 1024 + tid] = z;
        if (tid < K_CLS) s2sum[tid] = 0.f;
        if (tid == K_CLS) *ctr = 0u;
    }

    // per-thread histogram over 8 contiguous labels (int4 loads)
    const int base = tid * 8;
    const int4 ya = ((const int4*)y)[tid * 2];
    const int4 yb = ((const int4*)y)[tid * 2 + 1];
    int yy[8] = {ya.x, ya.y, ya.z, ya.w, yb.x, yb.y, yb.z, yb.w};
    int h[K_CLS];
#pragma unroll
    for (int k = 0; k < K_CLS; ++k) h[k] = 0;
#pragma unroll
    for (int i = 0; i < 8; ++i)
#pragma unroll
        for (int k = 0; k < K_CLS; ++k) h[k] += (yy[i] == k) ? 1 : 0;
#pragma unroll
    for (int k = 0; k < K_CLS; ++k) M[k * 1024 + tid] = h[k];
    __syncthreads();

    // block exclusive scan over M flat [10240], class-major
    int loc[K_CLS];
    int run = 0;
#pragma unroll
    for (int j = 0; j < K_CLS; ++j) { loc[j] = run; run += M[tid * K_CLS + j]; }
    int v = run;
#pragma unroll
    for (int d = 1; d < 64; d <<= 1) {
        int n = __shfl_up(v, d, 64);
        if (lane >= d) v += n;
    }
    if (lane == 63) wsum[wid] = v;
    __syncthreads();
    int wbase = 0;
#pragma unroll
    for (int w = 0; w < 16; ++w) wbase += (w < wid) ? wsum[w] : 0;
    const int tbase = wbase + (v - run);
    __syncthreads();
#pragma unroll
    for (int j = 0; j < K_CLS; ++j) M[tid * K_CLS + j] = tbase + loc[j];
    __syncthreads();

    if (tid < K_CLS) {
        const int s = M[tid * 1024];
        const int e = (tid == K_CLS - 1) ? N_SAMP : M[(tid + 1) * 1024];
        counts[tid] = e - s;
    }

    // stable scatter, class packed in high bits
    int off[K_CLS];
#pragma unroll
    for (int k = 0; k < K_CLS; ++k) off[k] = M[k * 1024 + tid];
#pragma unroll
    for (int i = 0; i < 8; ++i)
#pragma unroll
        for (int k = 0; k < K_CLS; ++k)
            if (yy[i] == k) sorted[off[k]++] = (k << 16) | (base + i);
}

// Kernel B: one block = one full 32-sample sorted window x one 1024-col slice.
// 1536 blocks = exactly 6/CU. 8-deep rotating register load pipeline
// (nontemporal: X is streamed exactly once, keep L2 for the S1 atomics).
// Class boundary inside a window is rare (<=9 across all 256 windows) and
// block-uniform -> scalar branch with block-reduced s2 flush.
// The LAST block to finish (global arrival ticket) runs the finish reduction
// in-place (fuses the old wcss_finish kernel + removes the out memset).
__global__ __launch_bounds__(256) void wcss_accum(const float* __restrict__ X,
                                                  const int* __restrict__ sorted,
                                                  const int* __restrict__ counts,
                                                  float* __restrict__ S1,
                                                  float* __restrict__ s2sum,
                                                  unsigned* __restrict__ ctr,
                                                  float* __restrict__ out) {
    __shared__ int off_lds[CHUNK];   // row byte-offsets
    __shared__ int cls_lds[CHUNK];
    __shared__ float wred[4];
    __shared__ int last_s;
    const int tid = threadIdx.x;
    const int lane = tid & 63;
    const int wid = tid >> 6;
    const int col0 = blockIdx.x * COLS_PER_BLOCK + tid * 4;

    if (tid < CHUNK) {
        const int p = sorted[blockIdx.y * CHUNK + tid];
        off_lds[tid] = (p & 0xffff) * (D_DIM * (int)sizeof(float));
        cls_lds[tid] = p >> 16;
    }
    __syncthreads();

    const char* basep = (const char*)(X + col0);
    f4 a1 = {0.f, 0.f, 0.f, 0.f};
    float s2c = 0.f;
    int kcur = __builtin_amdgcn_readfirstlane(cls_lds[0]);

    f4 buf[PIPE];
#pragma unroll
    for (int j = 0; j < PIPE; ++j)
        buf[j] = __builtin_nontemporal_load(
            (const f4*)(basep + (size_t)off_lds[j]));

#pragma unroll
    for (int s = 0; s < CHUNK; ++s) {
        const f4 v = buf[s & (PIPE - 1)];
        if (s + PIPE < CHUNK)   // compile-time after full unroll
            buf[s & (PIPE - 1)] = __builtin_nontemporal_load(
                (const f4*)(basep + (size_t)off_lds[s + PIPE]));

        const int yk = __builtin_amdgcn_readfirstlane(cls_lds[s]);
        if (yk != kcur) {   // block-uniform scalar branch, rare
            float* b1 = S1 + kcur * D_DIM + col0;
            atomicAdd(b1 + 0, a1.x); atomicAdd(b1 + 1, a1.y);
            atomicAdd(b1 + 2, a1.z); atomicAdd(b1 + 3, a1.w);
            float r = s2c;
#pragma unroll
            for (int o = 32; o > 0; o >>= 1) r += __shfl_down(r, o, 64);
            if (lane == 0) wred[wid] = r;
            __syncthreads();   // legal: branch is block-uniform
            if (tid == 0)
                atomicAdd(&s2sum[kcur], wred[0] + wred[1] + wred[2] + wred[3]);
            __syncthreads();
            a1 = (f4){0.f, 0.f, 0.f, 0.f};
            s2c = 0.f;
            kcur = yk;
        }
        a1 += v;
        s2c += v.x * v.x + v.y * v.y + v.z * v.z + v.w * v.w;
    }

    // final flush
    float* b1 = S1 + kcur * D_DIM + col0;
    atomicAdd(b1 + 0, a1.x); atomicAdd(b1 + 1, a1.y);
    atomicAdd(b1 + 2, a1.z); atomicAdd(b1 + 3, a1.w);
#pragma unroll
    for (int o = 32; o > 0; o >>= 1) s2c += __shfl_down(s2c, o, 64);
    if (lane == 0) wred[wid] = s2c;
    __syncthreads();
    if (tid == 0)
        atomicAdd(&s2sum[kcur], wred[0] + wred[1] + wred[2] + wred[3]);

    // ---- last-block fused finish ----
    __threadfence();                       // release our S1/s2sum atomics
    if (tid == 0) {
        unsigned t = atomicAdd(ctr, 1u);
        last_s = (t == (unsigned)(NBLK - 1)) ? 1 : 0;
    }
    __syncthreads();
    if (!last_s) return;
    __threadfence();                       // acquire side

    // total = sum_k [ s2sum_k/(c_k*D*K) - sum_col S1[k,col]^2/(c_k^2*D*K) ]
    float part = 0.f;
#pragma unroll
    for (int k = 0; k < K_CLS; ++k) {
        const float c = (float)counts[k];
        const float inv2 = 1.0f / (c * c * (float)D_DIM * (float)K_CLS);
        const float* Sk = S1 + k * D_DIM;
        for (int j = 0; j < D_DIM / 256; ++j) {    // 24 coalesced agent loads
            float vv = __hip_atomic_load(&Sk[j * 256 + tid], __ATOMIC_RELAXED,
                                         __HIP_MEMORY_SCOPE_AGENT);
            part -= vv * vv * inv2;
        }
        if (tid == 0)
            part += __hip_atomic_load(&s2sum[k], __ATOMIC_RELAXED,
                                      __HIP_MEMORY_SCOPE_AGENT) /
                    (c * (float)D_DIM * (float)K_CLS);
    }
    float r = part;
#pragma unroll
    for (int o = 32; o > 0; o >>= 1) r += __shfl_down(r, o, 64);
    if (lane == 0) wred[wid] = r;
    __syncthreads();
    if (tid == 0) *out = wred[0] + wred[1] + wred[2] + wred[3];
}

extern "C" void kernel_launch(void* const* d_in, const int* in_sizes, int n_in,
                              void* d_out, int out_size, void* d_ws, size_t ws_size,
                              hipStream_t stream) {
    const float* X = (const float*)d_in[0];
    const int* y = (const int*)d_in[1];

    float* S1 = (float*)d_ws;                       // K*D floats
    float* s2sum = S1 + K_CLS * D_DIM;              // K floats
    int* counts = (int*)(s2sum + K_CLS);            // K ints
    int* sorted = counts + K_CLS;                   // N ints
    unsigned* ctr = (unsigned*)(sorted + N_SAMP);   // 1 uint (arrival ticket)
    float* out = (float*)d_out;

    // 2 dispatches total (was 5: two memsets + three kernels).
    build_sort<<<dim3(1), dim3(1024), 0, stream>>>(y, counts, sorted,
                                                   S1, s2sum, ctr);
    wcss_accum<<<dim3(NGROUPS, NWIN), dim3(256), 0, stream>>>(X, sorted, counts,
                                                              S1, s2sum, ctr, out);
}

// Round 2
// 301.039 us; speedup vs baseline: 2.0454x; 2.0454x over previous
//
#include <hip/hip_runtime.h>

#define N_SAMP 8192
#define D_DIM 6144
#define K_CLS 10
#define CHUNK 32
#define NWIN (N_SAMP / CHUNK)             // 256 windows, always full
#define COLS_PER_BLOCK 1024               // 256 threads * 4 floats
#define NGROUPS (D_DIM / COLS_PER_BLOCK)  // 6  -> grid 1536 = 6 blocks/CU even
#define NBLK (NGROUPS * NWIN)             // 1536 accum blocks
#define PIPE 8                            // outstanding float4 loads per thread

typedef float f4 __attribute__((ext_vector_type(4)));

// Device-scope atomic add: performed at the device-coherent point (no XCD-L2
// dirtying -> no buffer_wbl2 needed anywhere). atomicAdd is device-scope by
// default on gfx950 (m20), but the explicit scope makes the codegen (sc flags)
// deterministic so the ticket ordering argument below is airtight.
__device__ inline void atom_add_dev(float* p, float v) {
    __hip_atomic_fetch_add(p, v, __ATOMIC_RELAXED, __HIP_MEMORY_SCOPE_AGENT);
}
__device__ inline float load_dev(const float* p) {
    return __hip_atomic_load(p, __ATOMIC_RELAXED, __HIP_MEMORY_SCOPE_AGENT);
}

// Kernel A: 1024-thread atomic-free counting sort by class, with fused
// zero-init of S1/s2sum/ctr (replaces two hipMemsetAsync dispatches).
// sorted[] packs (class<<16 | sample idx), class-contiguous. counts[k] out.
__global__ __launch_bounds__(1024) void build_sort(const int* __restrict__ y,
                                                   int* __restrict__ counts,
                                                   int* __restrict__ sorted,
                                                   float* __restrict__ S1,
                                                   float* __restrict__ s2sum,
                                                   unsigned* __restrict__ ctr) {
    __shared__ int M[K_CLS * 1024];
    __shared__ int wsum[16];
    const int tid = threadIdx.x;
    const int lane = tid & 63;
    const int wid = tid >> 6;

    // ---- fused zero-init: S1 (61440 f) + s2sum (10 f) + arrival ctr ----
    {
        f4 z = {0.f, 0.f, 0.f, 0.f};
        f4* p = (f4*)S1;
#pragma unroll
        for (int i = 0; i < (K_CLS * D_DIM) / (4 * 1024); ++i)  // 15 per thread
            p[i * 1024 + tid] = z;
        if (tid < K_CLS) s2sum[tid] = 0.f;
        if (tid == K_CLS) *ctr = 0u;
    }

    // per-thread histogram over 8 contiguous labels (int4 loads)
    const int base = tid * 8;
    const int4 ya = ((const int4*)y)[tid * 2];
    const int4 yb = ((const int4*)y)[tid * 2 + 1];
    int yy[8] = {ya.x, ya.y, ya.z, ya.w, yb.x, yb.y, yb.z, yb.w};
    int h[K_CLS];
#pragma unroll
    for (int k = 0; k < K_CLS; ++k) h[k] = 0;
#pragma unroll
    for (int i = 0; i < 8; ++i)
#pragma unroll
        for (int k = 0; k < K_CLS; ++k) h[k] += (yy[i] == k) ? 1 : 0;
#pragma unroll
    for (int k = 0; k < K_CLS; ++k) M[k * 1024 + tid] = h[k];
    __syncthreads();

    // block exclusive scan over M flat [10240], class-major
    int loc[K_CLS];
    int run = 0;
#pragma unroll
    for (int j = 0; j < K_CLS; ++j) { loc[j] = run; run += M[tid * K_CLS + j]; }
    int v = run;
#pragma unroll
    for (int d = 1; d < 64; d <<= 1) {
        int n = __shfl_up(v, d, 64);
        if (lane >= d) v += n;
    }
    if (lane == 63) wsum[wid] = v;
    __syncthreads();
    int wbase = 0;
#pragma unroll
    for (int w = 0; w < 16; ++w) wbase += (w < wid) ? wsum[w] : 0;
    const int tbase = wbase + (v - run);
    __syncthreads();
#pragma unroll
    for (int j = 0; j < K_CLS; ++j) M[tid * K_CLS + j] = tbase + loc[j];
    __syncthreads();

    if (tid < K_CLS) {
        const int s = M[tid * 1024];
        const int e = (tid == K_CLS - 1) ? N_SAMP : M[(tid + 1) * 1024];
        counts[tid] = e - s;
    }

    // stable scatter, class packed in high bits
    int off[K_CLS];
#pragma unroll
    for (int k = 0; k < K_CLS; ++k) off[k] = M[k * 1024 + tid];
#pragma unroll
    for (int i = 0; i < 8; ++i)
#pragma unroll
        for (int k = 0; k < K_CLS; ++k)
            if (yy[i] == k) sorted[off[k]++] = (k << 16) | (base + i);
}

// Kernel B: one block = one full 32-sample sorted window x one 1024-col slice.
// 1536 blocks = exactly 6/CU. 8-deep rotating register load pipeline (plain
// cached loads -- nt regressed in r1). Class boundary inside a window is rare
// (<=9 across all 256 windows) and block-uniform -> scalar branch.
// Last block (global arrival ticket) runs the finish reduction in-place.
// NO __threadfence(): r1 showed per-block agent fences (buffer_wbl2/inv) cost
// 3.5x (WRITE_SIZE 25.5 MB of repeated L2 writebacks). Instead all shared
// accumulators use device-scope atomics (coherent point, never dirty XCD L2)
// and ordering is per-wave s_waitcnt vmcnt(0) + __syncthreads before ticket.
__global__ __launch_bounds__(256) void wcss_accum(const float* __restrict__ X,
                                                  const int* __restrict__ sorted,
                                                  const int* __restrict__ counts,
                                                  float* __restrict__ S1,
                                                  float* __restrict__ s2sum,
                                                  unsigned* __restrict__ ctr,
                                                  float* __restrict__ out) {
    __shared__ int off_lds[CHUNK];   // row byte-offsets
    __shared__ int cls_lds[CHUNK];
    __shared__ float wred[4];
    __shared__ int last_s;
    const int tid = threadIdx.x;
    const int lane = tid & 63;
    const int wid = tid >> 6;
    const int col0 = blockIdx.x * COLS_PER_BLOCK + tid * 4;

    if (tid < CHUNK) {
        const int p = sorted[blockIdx.y * CHUNK + tid];
        off_lds[tid] = (p & 0xffff) * (D_DIM * (int)sizeof(float));
        cls_lds[tid] = p >> 16;
    }
    __syncthreads();

    const char* basep = (const char*)(X + col0);
    f4 a1 = {0.f, 0.f, 0.f, 0.f};
    float s2c = 0.f;
    int kcur = __builtin_amdgcn_readfirstlane(cls_lds[0]);

    f4 buf[PIPE];
#pragma unroll
    for (int j = 0; j < PIPE; ++j)
        buf[j] = *(const f4*)(basep + (size_t)off_lds[j]);

#pragma unroll
    for (int s = 0; s < CHUNK; ++s) {
        const f4 v = buf[s & (PIPE - 1)];
        if (s + PIPE < CHUNK)   // compile-time after full unroll
            buf[s & (PIPE - 1)] =
                *(const f4*)(basep + (size_t)off_lds[s + PIPE]);

        const int yk = __builtin_amdgcn_readfirstlane(cls_lds[s]);
        if (yk != kcur) {   // block-uniform scalar branch, rare
            float* b1 = S1 + kcur * D_DIM + col0;
            atom_add_dev(b1 + 0, a1.x); atom_add_dev(b1 + 1, a1.y);
            atom_add_dev(b1 + 2, a1.z); atom_add_dev(b1 + 3, a1.w);
            float r = s2c;
#pragma unroll
            for (int o = 32; o > 0; o >>= 1) r += __shfl_down(r, o, 64);
            if (lane == 0) wred[wid] = r;
            __syncthreads();   // legal: branch is block-uniform
            if (tid == 0)
                atom_add_dev(&s2sum[kcur],
                             wred[0] + wred[1] + wred[2] + wred[3]);
            __syncthreads();
            a1 = (f4){0.f, 0.f, 0.f, 0.f};
            s2c = 0.f;
            kcur = yk;
        }
        a1 += v;
        s2c += v.x * v.x + v.y * v.y + v.z * v.z + v.w * v.w;
    }

    // final flush
    float* b1 = S1 + kcur * D_DIM + col0;
    atom_add_dev(b1 + 0, a1.x); atom_add_dev(b1 + 1, a1.y);
    atom_add_dev(b1 + 2, a1.z); atom_add_dev(b1 + 3, a1.w);
#pragma unroll
    for (int o = 32; o > 0; o >>= 1) s2c += __shfl_down(s2c, o, 64);
    if (lane == 0) wred[wid] = s2c;
    // my wave's device-scope atomics have completed at the coherent point:
    asm volatile("s_waitcnt vmcnt(0)" ::: "memory");
    __syncthreads();        // => ALL waves of this block have completed theirs
    if (tid == 0) {
        atom_add_dev(&s2sum[kcur], wred[0] + wred[1] + wred[2] + wred[3]);
        asm volatile("s_waitcnt vmcnt(0)" ::: "memory");
        unsigned t = __hip_atomic_fetch_add(ctr, 1u, __ATOMIC_RELAXED,
                                            __HIP_MEMORY_SCOPE_AGENT);
        last_s = (t == (unsigned)(NBLK - 1)) ? 1 : 0;
    }
    __syncthreads();
    if (!last_s) return;

    // ---- last-block fused finish (agent-scope loads bypass stale caches) ----
    // total = sum_k [ s2sum_k/(c_k*D*K) - sum_col S1[k,col]^2/(c_k^2*D*K) ]
    float part = 0.f;
#pragma unroll
    for (int k = 0; k < K_CLS; ++k) {
        const float c = (float)counts[k];
        const float inv2 = 1.0f / (c * c * (float)D_DIM * (float)K_CLS);
        const float* Sk = S1 + k * D_DIM;
        for (int j = 0; j < D_DIM / 256; ++j) {    // 24 coalesced agent loads
            float vv = load_dev(&Sk[j * 256 + tid]);
            part -= vv * vv * inv2;
        }
        if (tid == 0)
            part += load_dev(&s2sum[k]) / (c * (float)D_DIM * (float)K_CLS);
    }
    float r = part;
#pragma unroll
    for (int o = 32; o > 0; o >>= 1) r += __shfl_down(r, o, 64);
    if (lane == 0) wred[wid] = r;
    __syncthreads();
    if (tid == 0) *out = wred[0] + wred[1] + wred[2] + wred[3];
}

extern "C" void kernel_launch(void* const* d_in, const int* in_sizes, int n_in,
                              void* d_out, int out_size, void* d_ws, size_t ws_size,
                              hipStream_t stream) {
    const float* X = (const float*)d_in[0];
    const int* y = (const int*)d_in[1];

    float* S1 = (float*)d_ws;                       // K*D floats
    float* s2sum = S1 + K_CLS * D_DIM;              // K floats
    int* counts = (int*)(s2sum + K_CLS);            // K ints
    int* sorted = counts + K_CLS;                   // N ints
    unsigned* ctr = (unsigned*)(sorted + N_SAMP);   // 1 uint (arrival ticket)
    float* out = (float*)d_out;

    // 2 dispatches total (was 5: two memsets + three kernels).
    build_sort<<<dim3(1), dim3(1024), 0, stream>>>(y, counts, sorted,
                                                   S1, s2sum, ctr);
    wcss_accum<<<dim3(NGROUPS, NWIN), dim3(256), 0, stream>>>(X, sorted, counts,
                                                              S1, s2sum, ctr, out);
}